// Round 1
// baseline (977.136 us; speedup 1.0000x reference)
//
#include <hip/hip_runtime.h>

#define IN_CAPS 1152
#define OUT_CH 32
#define PAD 33                 // +1 pad: LDS bank = (i + j) % 32 -> conflict-free
#define BLOCK 576              // 9 waves; 1152/576 = 2 rows per thread exactly
#define NWAVES (BLOCK / 64)
#define ROWS_PER_THREAD (IN_CAPS / BLOCK)
#define F4_PER_THREAD (IN_CAPS * OUT_CH / 4 / BLOCK)   // 16
#define EPS 1e-8f

__global__ __launch_bounds__(BLOCK, 3)
void caps_route(const float* __restrict__ u_hat,
                const float* __restrict__ c0,
                const int* __restrict__ routings_p,
                float* __restrict__ out)
{
    __shared__ float u_s[IN_CAPS * PAD];       // 152,064 B
    __shared__ float swred[NWAVES * OUT_CH];   // 1,152 B
    __shared__ float vsh[OUT_CH];              // 128 B

    const int t = threadIdx.x;
    const int n = blockIdx.x;
    const int lane = t & 63;
    const int wave = t >> 6;

    const float4* __restrict__ u4 =
        reinterpret_cast<const float4*>(u_hat) + (size_t)n * (IN_CAPS * OUT_CH / 4);
    const float4* __restrict__ c4 = reinterpret_cast<const float4*>(c0);

    // ---------- staging into LDS, fused with pass 1: s = sum_i u[i,:] * c0[i,:] ----------
    // flat float4 index f = t + k*BLOCK: perfectly coalesced. Channel group of this
    // thread is fixed: j0 = (t & 7) * 4 (since BLOCK % 8 == 0).
    float p0 = 0.f, p1 = 0.f, p2 = 0.f, p3 = 0.f;
    #pragma unroll
    for (int k = 0; k < F4_PER_THREAD; ++k) {
        int f = t + k * BLOCK;
        float4 a = u4[f];
        float4 w = c4[f];
        int i  = f >> 3;
        int j0 = (f & 7) << 2;
        float* dst = &u_s[i * PAD + j0];
        dst[0] = a.x; dst[1] = a.y; dst[2] = a.z; dst[3] = a.w;
        p0 = fmaf(a.x, w.x, p0);
        p1 = fmaf(a.y, w.y, p1);
        p2 = fmaf(a.z, w.z, p2);
        p3 = fmaf(a.w, w.w, p3);
    }
    // lanes sharing (lane & 7) hold partials for the same 4 channels: reduce over masks 8,16,32
    #pragma unroll
    for (int m = 8; m <= 32; m <<= 1) {
        p0 += __shfl_xor(p0, m);
        p1 += __shfl_xor(p1, m);
        p2 += __shfl_xor(p2, m);
        p3 += __shfl_xor(p3, m);
    }
    if (lane < 8) {
        swred[wave * OUT_CH + lane * 4 + 0] = p0;
        swred[wave * OUT_CH + lane * 4 + 1] = p1;
        swred[wave * OUT_CH + lane * 4 + 2] = p2;
        swred[wave * OUT_CH + lane * 4 + 3] = p3;
    }
    __syncthreads();
    // reduce across waves + squash -> vsh
    if (t < OUT_CH) {
        float s = 0.f;
        #pragma unroll
        for (int w = 0; w < NWAVES; ++w) s += swred[w * OUT_CH + t];
        float n2 = s * s;
        #pragma unroll
        for (int m = 1; m <= 16; m <<= 1) n2 += __shfl_xor(n2, m);
        float scale = n2 / ((1.0f + n2) * sqrtf(n2 + EPS));
        vsh[t] = s * scale;
    }
    __syncthreads();

    // ---------- routing passes: s_new = sum_i u[i,:] * softmax_j(u[i,:] * v) ----------
    const int iters = routings_p[0] - 1;
    for (int it = 0; it < iters; ++it) {
        float v[OUT_CH];
        #pragma unroll
        for (int j = 0; j < OUT_CH; ++j) v[j] = vsh[j];  // broadcast reads

        float acc[OUT_CH];
        #pragma unroll
        for (int j = 0; j < OUT_CH; ++j) acc[j] = 0.f;

        #pragma unroll
        for (int s = 0; s < ROWS_PER_THREAD; ++s) {
            const int i = t + s * BLOCK;                 // strided rows: conflict-free LDS
            const float* row = &u_s[i * PAD];
            float rr[OUT_CH], e[OUT_CH];
            float sum = 0.f;
            // softmax over channels is thread-local; max-subtraction skipped
            // (|u*v| <~ 8, exp is safe in fp32, result mathematically identical)
            #pragma unroll
            for (int j = 0; j < OUT_CH; ++j) {
                rr[j] = row[j];
                e[j] = __expf(rr[j] * v[j]);
                sum += e[j];
            }
            float w = __builtin_amdgcn_rcpf(sum);
            #pragma unroll
            for (int j = 0; j < OUT_CH; ++j)
                acc[j] = fmaf(rr[j], e[j] * w, acc[j]);
        }

        // reduce acc across the 64-lane wave
        #pragma unroll
        for (int j = 0; j < OUT_CH; ++j) {
            #pragma unroll
            for (int m = 1; m <= 32; m <<= 1)
                acc[j] += __shfl_xor(acc[j], m);
        }
        if (lane == 0) {
            #pragma unroll
            for (int j = 0; j < OUT_CH; ++j) swred[wave * OUT_CH + j] = acc[j];
        }
        __syncthreads();
        if (t < OUT_CH) {
            float s = 0.f;
            #pragma unroll
            for (int w = 0; w < NWAVES; ++w) s += swred[w * OUT_CH + t];
            float n2 = s * s;
            #pragma unroll
            for (int m = 1; m <= 16; m <<= 1) n2 += __shfl_xor(n2, m);
            float scale = n2 / ((1.0f + n2) * sqrtf(n2 + EPS));
            vsh[t] = s * scale;
        }
        __syncthreads();
    }

    if (t < OUT_CH) {
        out[(size_t)n * OUT_CH + t] = vsh[t] * 0.5f + 0.5f;
    }
}

extern "C" void kernel_launch(void* const* d_in, const int* in_sizes, int n_in,
                              void* d_out, int out_size, void* d_ws, size_t ws_size,
                              hipStream_t stream) {
    const float* u_hat   = (const float*)d_in[0];
    const float* c0      = (const float*)d_in[1];
    const int*   routing = (const int*)d_in[2];
    float* out = (float*)d_out;

    const int N = in_sizes[0] / (IN_CAPS * OUT_CH);   // 4096
    caps_route<<<dim3(N), dim3(BLOCK), 0, stream>>>(u_hat, c0, routing, out);
}